// Round 8
// baseline (318.167 us; speedup 1.0000x reference)
//
#include <hip/hip_runtime.h>
#include <math.h>

namespace {

constexpr int Himg = 224, Wimg = 224, Cn = 3, Kk = 32;
constexpr int MAXT = 64;
constexpr int WSTRIDE = 512;               // ints per image in tap workspace
constexpr int IMG_F  = Himg * Wimg * Cn;   // 150528 floats per image
constexpr int ROW_F  = Wimg * Cn;          // 672 floats per row
constexpr int ROW_B  = ROW_F * 4;          // 2688 B

// ---- column-major LDS tile ----
// R7: row-major b32 = 0 conflicts but 32 DS slots/tap (4 B/lane each) ->
// DS-issue floor ~52 us. Column-major (col stride 63 words) makes a thread's
// 32 row-values CONSECUTIVE words -> 16x ds_read2_b32 per tap (2 words/slot),
// word-granular so NO alignment cases. gcd(63,32)=1 -> adjacent lanes hit
// distinct banks (2 lanes/bank, m136-free). Tap offset = one uniform add.
constexpr int TW_F = 224;                  // tile width in float-cols (672 = 3*224)
constexpr int TH = 32;                     // output rows per tile (224 = 7*32)
constexpr int TILES_X = 3;
constexpr int TILES_Y = 7;
constexpr int TPI = TILES_X * TILES_Y;     // 21 tiles per image
constexpr int L_W = 320;                   // cols: 224 + 2*48 halo (3*dkx in [-45,48])
constexpr int L_H = 63;                    // rows per col == col stride (words)
constexpr int L_SZ = L_W * L_H;            // 20160 floats = 80640 B

typedef float v4  __attribute__((ext_vector_type(4), aligned(4)));
typedef float v4a __attribute__((ext_vector_type(4), aligned(16)));

// ws per-image layout (ints): [0]=n  [1]=w  [2..65]=dky  [66..129]=dkx  [130..193]=xoff(bytes)

// ---------------- pre-pass: one tap list per image ----------------
__global__ __launch_bounds__(64)
void build_taps(const float* __restrict__ tbl,
                const int* __restrict__ amt,
                const int* __restrict__ ang,
                int* __restrict__ ws)
{
    const int b   = blockIdx.x;
    const int tid = threadIdx.x;

    __shared__ int   s_cnt;
    __shared__ float s_w;
    __shared__ int   s_dky[MAXT], s_dkx[MAXT];

    if (tid == 0) { s_cnt = 0; s_w = 0.0f; }
    __syncthreads();

    const int a = amt[b];
    // reference-exact numerics (verified absmax 0.0039 across all prior rounds)
    const float  rad = (float)ang[b] * (float)(M_PI / 180.0);
    const double rd  = (double)rad;
    const float  cth = (float)cos(rd);
    const float  sth = (float)sin(rd);
    const float  e   = 31.0f;
    const float xoff = __fmul_rn(__fsub_rn(e, __fsub_rn(__fmul_rn(cth, e), __fmul_rn(sth, e))), 0.5f);
    const float yoff = __fmul_rn(__fsub_rn(e, __fadd_rn(__fmul_rn(sth, e), __fmul_rn(cth, e))), 0.5f);

    for (int p = tid; p < Kk * Kk; p += 64) {
        const int   ky = p >> 5, kx = p & 31;
        const float xf = (float)kx, yf = (float)ky;
        const float sx = __fadd_rn(__fsub_rn(__fmul_rn(cth, xf), __fmul_rn(sth, yf)), xoff);
        const float sy = __fadd_rn(__fadd_rn(__fmul_rn(sth, xf), __fmul_rn(cth, yf)), yoff);
        const int ix = (int)rintf(sx);   // round-half-even == jnp.round
        const int iy = (int)rintf(sy);
        if (ix >= 0 && ix < Kk && iy >= 0 && iy < Kk) {
            const float v = tbl[((a * Kk + iy) * Kk + ix) * Cn];
            if (v != 0.0f) {
                const int idx = atomicAdd(&s_cnt, 1);
                if (idx < MAXT) {
                    s_dky[idx] = ky - 15;
                    s_dkx[idx] = kx - 15;
                    s_w = v;                 // benign race: all writers store 1/size
                }
            }
        }
    }
    __syncthreads();

    const int n = min(s_cnt, MAXT);
    int* wsb = ws + b * WSTRIDE;
    if (tid == 0) { wsb[0] = n; wsb[1] = __float_as_int(s_w); }
    for (int i = tid; i < n; i += 64) {
        wsb[2 + i]   = s_dky[i];
        wsb[66 + i]  = s_dkx[i];
        wsb[130 + i] = s_dky[i] * ROW_B + s_dkx[i] * (int)(Cn * sizeof(float));
    }
}

// ---------------- LDS-tiled conv, column-major / ds_read2 pairs ----------------
// Zero-padded tile => no masks in compute; OOB taps add 0.0 (bitwise-identical
// to masked adds). Per tap: ONE uniform v_add, then 32 consecutive-word reads
// (compiler merges to 16 ds_read2_b32) + 32 acc adds. Tap order preserved.
__global__ __launch_bounds__(256, 2)
void blur_cm(const float* __restrict__ x,
             const int* __restrict__ ws,
             float* __restrict__ out,
             int B)
{
    const int tid = threadIdx.x;
    const int L   = blockIdx.x;

    // XCD-pinned decode: image b handled entirely by XCD (b & 7). 2688 = 8*336.
    int b, t;
    if (B == 128) {
        const int xcd = L & 7;
        const int j   = L >> 3;
        const int g   = j / TPI;
        t = j - g * TPI;
        b = g * 8 + xcd;
    } else {
        b = L / TPI;
        t = L - b * TPI;
    }
    const int ty = t / TILES_X;            // 0..6
    const int tx = t - ty * TILES_X;       // 0..2
    const int y0 = ty * TH;                // first output row of tile
    const int g0 = tx * TW_F - 48;         // global float-col of LDS col 0
    const int r0 = y0 - 15;                // global row of LDS row 0

    __shared__ float lds[L_SZ];            // 80640 B, layout [col][row], stride 63
    __shared__ int   shNW[2];
    __shared__ int   s_tof[MAXT + 1];      // per-tap LDS byte offset (+1 for prefetch)

    const int* wsb = ws + b * WSTRIDE;
    if (tid < 2)    shNW[tid] = wsb[tid];
    if (tid < MAXT) {
        const int dky = wsb[2 + tid];
        const int dkx = wsb[66 + tid];
        s_tof[tid] = (3 * dkx * L_H + dky) * 4;   // col shift * stride + row shift, bytes
    }

    // ---- stage tile col-major, zero-padded. Lane l of a wave handles col
    // (lc0+l) at fixed row: global read = 64 consecutive words (coalesced,
    // 320%64==0 so no row straddle); ds_write bank = (-(col)+row)%32, 2/bank.
    const float* xb = x + (size_t)b * IMG_F;
    for (int u = tid; u < L_SZ; u += 256) {
        const int lr = u / L_W;                    // tile row
        const int lc = u - lr * L_W;               // tile col
        const int gr = r0 + lr;
        const int gc = g0 + lc;
        float val = 0.0f;
        if ((unsigned)gr < (unsigned)Himg && (unsigned)gc < (unsigned)ROW_F)
            val = xb[(size_t)gr * ROW_F + gc];
        lds[lc * L_H + lr] = val;
    }
    __syncthreads();

    const int   n = shNW[0];
    const float w = __int_as_float(shNW[1]);

    if (tid < TW_F) {                      // 224 active threads
        const char* ldsb  = (const char*)lds;
        const int   abase = ((48 + tid) * L_H + 15) * 4;   // own col, output row 0

        float acc[TH];
#pragma unroll
        for (int p = 0; p < TH; ++p) acc[p] = 0.0f;

        int tofn = s_tof[0];
        for (int i = 0; i < n; ++i) {
            const int tof = __builtin_amdgcn_readfirstlane(tofn);  // wave-uniform
            tofn = s_tof[i + 1];                  // prefetch next (broadcast read)
            const char* ap = ldsb + (abase + tof);
#pragma unroll
            for (int p = 0; p < TH; ++p) {
                acc[p] += *(const float*)(ap + 4 * p);   // consecutive words -> read2 pairs
            }
        }

        // ---- store: per instruction, lanes = consecutive cols (coalesced) ----
        float* ob = out + (size_t)b * IMG_F + (size_t)y0 * ROW_F + tx * TW_F + tid;
#pragma unroll
        for (int p = 0; p < TH; ++p) {
            __builtin_nontemporal_store(acc[p] * w, ob + p * ROW_F);
        }
    }
}

}  // namespace

extern "C" void kernel_launch(void* const* d_in, const int* in_sizes, int n_in,
                              void* d_out, int out_size, void* d_ws, size_t ws_size,
                              hipStream_t stream) {
    const float* x   = (const float*)d_in[0];
    const float* tbl = (const float*)d_in[1];
    const int*   amt = (const int*)d_in[2];
    const int*   ang = (const int*)d_in[3];
    float*       out = (float*)d_out;
    int*         ws  = (int*)d_ws;

    const int B = in_sizes[2];  // 128

    build_taps<<<B, 64, 0, stream>>>(tbl, amt, ang, ws);
    blur_cm<<<B * TPI, 256, 0, stream>>>(x, ws, out, B);
}

// Round 9
// 216.694 us; speedup vs baseline: 1.4683x; 1.4683x over previous
//
#include <hip/hip_runtime.h>
#include <math.h>

namespace {

constexpr int Himg = 224, Wimg = 224, Cn = 3, Kk = 32;
constexpr int MAXT = 64;
constexpr int WSTRIDE = 512;               // ints per image in tap workspace
constexpr int IMG_F  = Himg * Wimg * Cn;   // 150528 floats per image
constexpr int ROW_F  = Wimg * Cn;          // 672 floats per row
constexpr int ROW_B  = ROW_F * 4;          // 2688 B

// ---- R7 tile (row-major, lane=float-col, static 1280B row offsets) ----
// Unified VMEM model (R0-R8): ~1 VMEM wave-instruction per ~73 cyc per CU,
// independent of width. R7 budget: DS 52us + stage 25us (79 dwordx4) +
// STORES 36us (112 scalar b32!). R9 = R7 + LDS store-transpose so stores
// become 28 dwordx4 wave-instr.
constexpr int TW_F = 224;                  // tile width in float-cols (672 = 3*224)
constexpr int TH = 32;                     // output rows per tile (224 = 7*32)
constexpr int TILES_X = 3;
constexpr int TILES_Y = 7;
constexpr int TPI = TILES_X * TILES_Y;     // 21 tiles per image
constexpr int L_W = 320;                   // 224 + 2*48 halo
constexpr int L_H = TH + 31;               // 63 rows (dky in [-15,16])
constexpr int L_SZ = L_W * L_H;            // 20160 floats = 80640 B
constexpr int T_STR = 228;                 // transpose row stride (mult of 4, !=0 mod 32)

typedef float v4  __attribute__((ext_vector_type(4), aligned(4)));
typedef float v4a __attribute__((ext_vector_type(4), aligned(16)));

// ws per-image layout (ints): [0]=n  [1]=w  [2..65]=dky  [66..129]=dkx  [130..193]=xoff(bytes)

// ---------------- pre-pass: one tap list per image ----------------
__global__ __launch_bounds__(64)
void build_taps(const float* __restrict__ tbl,
                const int* __restrict__ amt,
                const int* __restrict__ ang,
                int* __restrict__ ws)
{
    const int b   = blockIdx.x;
    const int tid = threadIdx.x;

    __shared__ int   s_cnt;
    __shared__ float s_w;
    __shared__ int   s_dky[MAXT], s_dkx[MAXT];

    if (tid == 0) { s_cnt = 0; s_w = 0.0f; }
    __syncthreads();

    const int a = amt[b];
    // reference-exact numerics (verified absmax 0.0039 across all prior rounds)
    const float  rad = (float)ang[b] * (float)(M_PI / 180.0);
    const double rd  = (double)rad;
    const float  cth = (float)cos(rd);
    const float  sth = (float)sin(rd);
    const float  e   = 31.0f;
    const float xoff = __fmul_rn(__fsub_rn(e, __fsub_rn(__fmul_rn(cth, e), __fmul_rn(sth, e))), 0.5f);
    const float yoff = __fmul_rn(__fsub_rn(e, __fadd_rn(__fmul_rn(sth, e), __fmul_rn(cth, e))), 0.5f);

    for (int p = tid; p < Kk * Kk; p += 64) {
        const int   ky = p >> 5, kx = p & 31;
        const float xf = (float)kx, yf = (float)ky;
        const float sx = __fadd_rn(__fsub_rn(__fmul_rn(cth, xf), __fmul_rn(sth, yf)), xoff);
        const float sy = __fadd_rn(__fadd_rn(__fmul_rn(sth, xf), __fmul_rn(cth, yf)), yoff);
        const int ix = (int)rintf(sx);   // round-half-even == jnp.round
        const int iy = (int)rintf(sy);
        if (ix >= 0 && ix < Kk && iy >= 0 && iy < Kk) {
            const float v = tbl[((a * Kk + iy) * Kk + ix) * Cn];
            if (v != 0.0f) {
                const int idx = atomicAdd(&s_cnt, 1);
                if (idx < MAXT) {
                    s_dky[idx] = ky - 15;
                    s_dkx[idx] = kx - 15;
                    s_w = v;                 // benign race: all writers store 1/size
                }
            }
        }
    }
    __syncthreads();

    const int n = min(s_cnt, MAXT);
    int* wsb = ws + b * WSTRIDE;
    if (tid == 0) { wsb[0] = n; wsb[1] = __float_as_int(s_w); }
    for (int i = tid; i < n; i += 64) {
        wsb[2 + i]   = s_dky[i];
        wsb[66 + i]  = s_dkx[i];
        wsb[130 + i] = s_dky[i] * ROW_B + s_dkx[i] * (int)(Cn * sizeof(float));
    }
}

// ---------------- LDS-tiled conv (R7) + vectorized store epilogue ----------------
// Compute identical to R7 (0 conflicts, static offset:p*1280 reads, one uniform
// v_add per tap). Epilogue: acc -> LDS (lane-stride-4B writes, free) -> b128
// reads -> dwordx4 coalesced stores. 112 scalar store-instr -> 28 dwordx4.
__global__ __launch_bounds__(256, 2)
void blur_colT(const float* __restrict__ x,
               const int* __restrict__ ws,
               float* __restrict__ out,
               int B)
{
    const int tid = threadIdx.x;
    const int L   = blockIdx.x;

    // XCD-pinned decode: image b handled entirely by XCD (b & 7). 2688 = 8*336.
    int b, t;
    if (B == 128) {
        const int xcd = L & 7;
        const int j   = L >> 3;
        const int g   = j / TPI;
        t = j - g * TPI;
        b = g * 8 + xcd;
    } else {
        b = L / TPI;
        t = L - b * TPI;
    }
    const int ty = t / TILES_X;            // 0..6
    const int tx = t - ty * TILES_X;       // 0..2
    const int y0 = ty * TH;                // first output row of tile
    const int g0 = tx * TW_F - 48;         // global float-col of LDS col 0 (mult of 4)
    const int r0 = y0 - 15;                // global row of LDS row 0

    __shared__ __align__(16) float lds[L_SZ];   // 80640 B (reused by epilogue)
    __shared__ int   shNW[2];
    __shared__ int   s_tof[MAXT + 1];      // per-tap LDS byte offset (+1 for prefetch)

    const int* wsb = ws + b * WSTRIDE;
    if (tid < 2)    shNW[tid] = wsb[tid];
    if (tid < MAXT) {
        const int dky = wsb[2 + tid];
        const int dkx = wsb[66 + tid];
        s_tof[tid] = (dky * L_W + 3 * dkx) * 4;   // bytes
    }

    // ---- stage tile: 63 rows x 80 v4-chunks, zero-padded outside the image ----
    const float* xb = x + (size_t)b * IMG_F;
    for (int u = tid; u < L_H * 80; u += 256) {
        const int lr  = u / 80;
        const int lc4 = (u - lr * 80) * 4;         // LDS float col, multiple of 4
        const int gr  = r0 + lr;
        const int gc  = g0 + lc4;                  // multiple of 4
        v4 val = {0.0f, 0.0f, 0.0f, 0.0f};
        if ((unsigned)gr < (unsigned)Himg && (unsigned)gc < (unsigned)ROW_F)
            val = *(const v4a*)(xb + (size_t)gr * ROW_F + gc);
        *(v4a*)(&lds[lr * L_W + lc4]) = val;
    }
    __syncthreads();

    const int   n = shNW[0];
    const float w = __int_as_float(shNW[1]);

    float acc[TH];
#pragma unroll
    for (int p = 0; p < TH; ++p) acc[p] = 0.0f;

    if (tid < TW_F) {                      // 224 active threads
        const char* ldsb  = (const char*)lds;
        const int   abase = (15 * L_W + 48 + tid) * 4;   // row 15, own col, bytes

        int tofn = s_tof[0];
        for (int i = 0; i < n; ++i) {
            const int tof = __builtin_amdgcn_readfirstlane(tofn);  // wave-uniform
            tofn = s_tof[i + 1];                  // prefetch next (broadcast read)
            const char* ap = ldsb + (abase + tof);
#pragma unroll
            for (int p = 0; p < TH; ++p) {
                acc[p] += *(const float*)(ap + p * (L_W * 4));   // static offset imm
            }
        }
    }

    // ---- epilogue: transpose through LDS, store dwordx4 coalesced ----
    // Tile data fully consumed -> safe to reuse lds after this barrier.
    __syncthreads();
#pragma unroll
    for (int h = 0; h < 2; ++h) {
        if (h) __syncthreads();                    // protect reuse between halves
        if (tid < TW_F) {
#pragma unroll
            for (int q = 0; q < 16; ++q)           // lane-stride-4B writes: free
                lds[q * T_STR + tid] = acc[h * 16 + q] * w;
        }
        __syncthreads();
        // 896 v4 items: r = v/56 (row in half), c4 = v%56 (v4 chunk)
        for (int v = tid; v < (TW_F / 4) * 16; v += 256) {
            const int r  = v / (TW_F / 4);
            const int c4 = v - r * (TW_F / 4);
            const v4 tv = *(const v4a*)(&lds[r * T_STR + 4 * c4]);
            float* op = out + (size_t)b * IMG_F
                      + (size_t)(y0 + h * 16 + r) * ROW_F + tx * TW_F + 4 * c4;
            __builtin_nontemporal_store(v4a{tv.x, tv.y, tv.z, tv.w}, (v4a*)op);
        }
    }
}

}  // namespace

extern "C" void kernel_launch(void* const* d_in, const int* in_sizes, int n_in,
                              void* d_out, int out_size, void* d_ws, size_t ws_size,
                              hipStream_t stream) {
    const float* x   = (const float*)d_in[0];
    const float* tbl = (const float*)d_in[1];
    const int*   amt = (const int*)d_in[2];
    const int*   ang = (const int*)d_in[3];
    float*       out = (float*)d_out;
    int*         ws  = (int*)d_ws;

    const int B = in_sizes[2];  // 128

    build_taps<<<B, 64, 0, stream>>>(tbl, amt, ang, ws);
    blur_colT<<<B * TPI, 256, 0, stream>>>(x, ws, out, B);
}

// Round 10
// 185.746 us; speedup vs baseline: 1.7129x; 1.1666x over previous
//
#include <hip/hip_runtime.h>
#include <math.h>

namespace {

constexpr int Himg = 224, Wimg = 224, Cn = 3, Kk = 32;
constexpr int MAXT = 64;
constexpr int WSTRIDE = 512;               // ints per image in tap workspace
constexpr int IMG_F  = Himg * Wimg * Cn;   // 150528 floats per image
constexpr int ROW_F  = Wimg * Cn;          // 672 floats per row
constexpr int ROW_B  = ROW_F * 4;          // 2688 B

// ---- R7 tile geometry, 8-wave blocks ----
// Model (R0-R9): loads cost ~73 cyc/wave-instr/CU (MSHR-rate); stores are
// free-streaming (R9). R7's compute loads likely merge to ds_read2st64
// (static 1280B=5x256B offsets), so DS issue is ~30-50us of its 100us ->
// residual is LATENCY DUTY at ~6 waves/CU. R10: same tile, 512-thread
// blocks (rows split 2 ways) -> 16 waves/CU, half work per wave.
constexpr int TW_F = 224;                  // tile width in float-cols (672 = 3*224)
constexpr int TH = 32;                     // output rows per tile (224 = 7*32)
constexpr int RH = 16;                     // rows per thread (TH/2)
constexpr int TILES_X = 3;
constexpr int TILES_Y = 7;
constexpr int TPI = TILES_X * TILES_Y;     // 21 tiles per image
constexpr int L_W = 320;                   // 224 + 2*48 halo
constexpr int L_H = TH + 31;               // 63 rows (dky in [-15,16])
constexpr int L_SZ = L_W * L_H;            // 20160 floats = 80640 B

typedef float v4  __attribute__((ext_vector_type(4), aligned(4)));
typedef float v4a __attribute__((ext_vector_type(4), aligned(16)));

// ws per-image layout (ints): [0]=n  [1]=w  [2..65]=dky  [66..129]=dkx  [130..193]=xoff(bytes)

// ---------------- pre-pass: one tap list per image ----------------
__global__ __launch_bounds__(64)
void build_taps(const float* __restrict__ tbl,
                const int* __restrict__ amt,
                const int* __restrict__ ang,
                int* __restrict__ ws)
{
    const int b   = blockIdx.x;
    const int tid = threadIdx.x;

    __shared__ int   s_cnt;
    __shared__ float s_w;
    __shared__ int   s_dky[MAXT], s_dkx[MAXT];

    if (tid == 0) { s_cnt = 0; s_w = 0.0f; }
    __syncthreads();

    const int a = amt[b];
    // reference-exact numerics (verified absmax 0.0039 across all prior rounds)
    const float  rad = (float)ang[b] * (float)(M_PI / 180.0);
    const double rd  = (double)rad;
    const float  cth = (float)cos(rd);
    const float  sth = (float)sin(rd);
    const float  e   = 31.0f;
    const float xoff = __fmul_rn(__fsub_rn(e, __fsub_rn(__fmul_rn(cth, e), __fmul_rn(sth, e))), 0.5f);
    const float yoff = __fmul_rn(__fsub_rn(e, __fadd_rn(__fmul_rn(sth, e), __fmul_rn(cth, e))), 0.5f);

    for (int p = tid; p < Kk * Kk; p += 64) {
        const int   ky = p >> 5, kx = p & 31;
        const float xf = (float)kx, yf = (float)ky;
        const float sx = __fadd_rn(__fsub_rn(__fmul_rn(cth, xf), __fmul_rn(sth, yf)), xoff);
        const float sy = __fadd_rn(__fadd_rn(__fmul_rn(sth, xf), __fmul_rn(cth, yf)), yoff);
        const int ix = (int)rintf(sx);   // round-half-even == jnp.round
        const int iy = (int)rintf(sy);
        if (ix >= 0 && ix < Kk && iy >= 0 && iy < Kk) {
            const float v = tbl[((a * Kk + iy) * Kk + ix) * Cn];
            if (v != 0.0f) {
                const int idx = atomicAdd(&s_cnt, 1);
                if (idx < MAXT) {
                    s_dky[idx] = ky - 15;
                    s_dkx[idx] = kx - 15;
                    s_w = v;                 // benign race: all writers store 1/size
                }
            }
        }
    }
    __syncthreads();

    const int n = min(s_cnt, MAXT);
    int* wsb = ws + b * WSTRIDE;
    if (tid == 0) { wsb[0] = n; wsb[1] = __float_as_int(s_w); }
    for (int i = tid; i < n; i += 64) {
        wsb[2 + i]   = s_dky[i];
        wsb[66 + i]  = s_dkx[i];
        wsb[130 + i] = s_dky[i] * ROW_B + s_dkx[i] * (int)(Cn * sizeof(float));
    }
}

// ---------------- LDS-tiled conv, 8 waves/block (rows split 2 ways) ----------------
// Compute pattern identical to R7 per-thread except 16 rows not 32: per tap,
// ONE uniform v_add then 16 loads at static p*1280B offsets (read2st64-
// mergeable) + 16 adds. Zero-padded tile -> no masks; tap-ascending adds ->
// bitwise-identical numerics. Stores scalar direct (R9: stores are free).
__global__ __launch_bounds__(512, 2)
void blur_w8(const float* __restrict__ x,
             const int* __restrict__ ws,
             float* __restrict__ out,
             int B)
{
    const int tid = threadIdx.x;
    const int L   = blockIdx.x;

    // XCD-pinned decode: image b handled entirely by XCD (b & 7). 2688 = 8*336.
    int b, t;
    if (B == 128) {
        const int xcd = L & 7;
        const int j   = L >> 3;
        const int g   = j / TPI;
        t = j - g * TPI;
        b = g * 8 + xcd;
    } else {
        b = L / TPI;
        t = L - b * TPI;
    }
    const int ty = t / TILES_X;            // 0..6
    const int tx = t - ty * TILES_X;       // 0..2
    const int y0 = ty * TH;                // first output row of tile
    const int g0 = tx * TW_F - 48;         // global float-col of LDS col 0 (mult of 4)
    const int r0 = y0 - 15;                // global row of LDS row 0

    __shared__ float lds[L_SZ];            // 80640 B
    __shared__ int   shNW[2];
    __shared__ int   s_tof[MAXT + 1];      // per-tap LDS byte offset (+1 for prefetch)

    const int* wsb = ws + b * WSTRIDE;
    if (tid < 2)    shNW[tid] = wsb[tid];
    if (tid < MAXT) {
        const int dky = wsb[2 + tid];
        const int dkx = wsb[66 + tid];
        s_tof[tid] = (dky * L_W + 3 * dkx) * 4;   // bytes
    }

    // ---- stage tile: 63 rows x 80 v4-chunks, zero-padded outside the image ----
    const float* xb = x + (size_t)b * IMG_F;
    for (int u = tid; u < L_H * 80; u += 512) {
        const int lr  = u / 80;
        const int lc4 = (u - lr * 80) * 4;         // LDS float col, multiple of 4
        const int gr  = r0 + lr;
        const int gc  = g0 + lc4;                  // multiple of 4
        v4 val = {0.0f, 0.0f, 0.0f, 0.0f};
        if ((unsigned)gr < (unsigned)Himg && (unsigned)gc < (unsigned)ROW_F)
            val = *(const v4a*)(xb + (size_t)gr * ROW_F + gc);
        *(v4a*)(&lds[lr * L_W + lc4]) = val;
    }
    __syncthreads();

    const int   n = shNW[0];
    const float w = __int_as_float(shNW[1]);

    // thread -> (row-half, column): waves 0-3 rows 0..15, waves 4-7 rows 16..31
    const int half = tid >> 8;             // 0 or 1
    const int col  = tid - (half << 8);    // 0..255; active if < 224

    if (col < TW_F) {
        const char* ldsb  = (const char*)lds;
        const int   abase = ((15 + half * RH) * L_W + 48 + col) * 4;

        float acc[RH];
#pragma unroll
        for (int p = 0; p < RH; ++p) acc[p] = 0.0f;

        int tofn = s_tof[0];
        for (int i = 0; i < n; ++i) {
            const int tof = __builtin_amdgcn_readfirstlane(tofn);  // wave-uniform
            tofn = s_tof[i + 1];                  // prefetch next (broadcast read)
            const char* ap = ldsb + (abase + tof);
#pragma unroll
            for (int p = 0; p < RH; ++p) {
                acc[p] += *(const float*)(ap + p * (L_W * 4));   // 1280B = 5x256B: read2st64 pairs
            }
        }

        // ---- store: per instruction, lanes = consecutive cols (coalesced); free-streaming ----
        float* ob = out + (size_t)b * IMG_F + (size_t)(y0 + half * RH) * ROW_F + tx * TW_F + col;
#pragma unroll
        for (int p = 0; p < RH; ++p) {
            __builtin_nontemporal_store(acc[p] * w, ob + p * ROW_F);
        }
    }
}

}  // namespace

extern "C" void kernel_launch(void* const* d_in, const int* in_sizes, int n_in,
                              void* d_out, int out_size, void* d_ws, size_t ws_size,
                              hipStream_t stream) {
    const float* x   = (const float*)d_in[0];
    const float* tbl = (const float*)d_in[1];
    const int*   amt = (const int*)d_in[2];
    const int*   ang = (const int*)d_in[3];
    float*       out = (float*)d_out;
    int*         ws  = (int*)d_ws;

    const int B = in_sizes[2];  // 128

    build_taps<<<B, 64, 0, stream>>>(tbl, amt, ang, ws);
    blur_w8<<<B * TPI, 512, 0, stream>>>(x, ws, out, B);
}